// Round 10
// baseline (106.531 us; speedup 1.0000x reference)
//
#include <hip/hip_runtime.h>
#include <hip/hip_bf16.h>

// Sizes (fixed by the problem)
#define E_CNT 131072
#define NP_CNT 65536
#define D_P 80
#define D_C 48
#define D_ADD 16
#define K1 1152   // 144*8
#define K2 512    // 64*8
#define MAXDEG 32
#define XROW 152  // 144 x-values + 8 ea (f16)

typedef _Float16 f16x8 __attribute__((ext_vector_type(8)));
typedef _Float16 f16x2 __attribute__((ext_vector_type(2)));
typedef float f32x4 __attribute__((ext_vector_type(4)));

union F16x8U { f16x2 h2[4]; f16x8 v8; };
union U4F2  { uint4 u; f16x2 h2[4]; };

__device__ __forceinline__ float silu_f(float x){
  return x / (1.0f + __expf(-x));
}
__device__ __forceinline__ f16x2 pkrtz(float a, float b){
  return __builtin_bit_cast(f16x2, __builtin_amdgcn_cvt_pkrtz(a, b));
}
__device__ __forceinline__ unsigned pkrtz_u(float a, float b){
  return __builtin_bit_cast(unsigned, __builtin_amdgcn_cvt_pkrtz(a, b));
}

// ---------------------------------------------------------------------------
// K-permutation: logical k = f*8+g; physical k = ks*32 + q*8 + j.
// f(q,ks) = q*NKS + ks (NKS = KTOT/32), g = j. Applied identically to A and B.
// prep_w: Wt[h][ks*32+q*8+j] = W[(q*NKS+ks)*512 + j*64 + h]
// ---------------------------------------------------------------------------
__global__ void prep_w_kernel(const float* __restrict__ W1, const float* __restrict__ W2,
                              _Float16* __restrict__ wt1, _Float16* __restrict__ wt2){
  int id = blockIdx.x * 256 + threadIdx.x;
  if (id < 64 * K1){
    int h = id / K1, k = id - h * K1;
    int ks = k >> 5, rem = k & 31, q = rem >> 3, j = rem & 7;
    wt1[id] = (_Float16)W1[(q * 36 + ks) * 512 + j * 64 + h];
  } else {
    int id2 = id - 64 * K1;
    int h = id2 / K2, k = id2 - h * K2;
    int ks = k >> 5, rem = k & 31, q = rem >> 3, j = rem & 7;
    wt2[id2] = (_Float16)W2[(q * 16 + ks) * 512 + j * 64 + h];
  }
}

// ---------------------------------------------------------------------------
// CSR build: zero, slot-fill, 3-step scan -> off[] and perm[] (edges by dst)
// ---------------------------------------------------------------------------
__global__ void zero_cnt_kernel(int* __restrict__ cnt, int* __restrict__ bsum){
  const int gid = blockIdx.x * 256 + threadIdx.x;
  if (gid < NP_CNT) cnt[gid] = 0;
  else bsum[gid - NP_CNT] = 0;
}
__global__ void fill_slots_kernel(const int* __restrict__ eidx,
                                  int* __restrict__ cnt, int* __restrict__ slots){
  const int e = blockIdx.x * 256 + threadIdx.x;
  const int d = eidx[E_CNT + e];
  const int p = atomicAdd(&cnt[d], 1);
  if (p < MAXDEG) slots[d * MAXDEG + p] = e;
}
__global__ void scanA_kernel(const int* __restrict__ cnt, int* __restrict__ bsum){
  const int t = threadIdx.x;
  int v = min(cnt[blockIdx.x * 256 + t], MAXDEG);
  #pragma unroll
  for (int o = 32; o; o >>= 1) v += __shfl_down(v, o);
  __shared__ int s[4];
  if ((t & 63) == 0) s[t >> 6] = v;
  __syncthreads();
  if (t == 0) bsum[blockIdx.x] = s[0] + s[1] + s[2] + s[3];
}
__global__ void scanB_kernel(const int* __restrict__ bsum, int* __restrict__ boff){
  __shared__ int s[256];
  const int t = threadIdx.x;
  const int v = bsum[t];
  s[t] = v; __syncthreads();
  for (int o = 1; o < 256; o <<= 1){
    int x = (t >= o) ? s[t - o] : 0;
    __syncthreads();
    s[t] += x;
    __syncthreads();
  }
  boff[t] = s[t] - v;
}
__global__ void scanC_emit_kernel(const int* __restrict__ cnt, const int* __restrict__ slots,
                                  const int* __restrict__ boff,
                                  int* __restrict__ off, int* __restrict__ perm){
  __shared__ int s[256];
  const int t = threadIdx.x;
  const int n = blockIdx.x * 256 + t;
  const int v = min(cnt[n], MAXDEG);
  s[t] = v; __syncthreads();
  for (int o = 1; o < 256; o <<= 1){
    int x = (t >= o) ? s[t - o] : 0;
    __syncthreads();
    s[t] += x;
    __syncthreads();
  }
  const int o0 = boff[blockIdx.x] + s[t] - v;
  off[n] = o0;
  for (int j = 0; j < v; ++j) perm[o0 + j] = slots[n * MAXDEG + j];
}

// ---------------------------------------------------------------------------
// gather_perm: xgp[pos][0..151] f16 = concat(x_p[dst], x_c[src], addf[e], ea[e])
// in PERM (dst-sorted) order. 8 lanes/edge; dsts sorted -> x_p nearly streams;
// writes fully coalesced. GEMM reads xgp sequentially afterwards.
// ---------------------------------------------------------------------------
__global__ __launch_bounds__(256) void gather_perm_kernel(
    const float* __restrict__ x_p, const float* __restrict__ x_c,
    const float* __restrict__ addf, const float* __restrict__ ea,
    const int* __restrict__ eidx, const int* __restrict__ perm,
    _Float16* __restrict__ xgp)
{
  const int gid = blockIdx.x * 256 + threadIdx.x;
  const int pos = gid >> 3;
  const int r = gid & 7;
  const int e = perm[pos] & (E_CNT - 1);
  const int dst = eidx[E_CNT + e];
  const int src = eidx[e];
  const float* pP = x_p  + (size_t)dst * D_P;
  const float* pC = x_c  + (size_t)src * D_C;
  const float* pA = addf + (size_t)e   * D_ADD;
  const float* pE = ea   + (size_t)e   * 8;
  _Float16* orow = xgp + (size_t)pos * XROW;
  #pragma unroll
  for (int i = 0; i < 5; ++i){
    const int jq = r + 8 * i;          // float-quad index 0..37
    if (jq < 38){
      const float* p = (jq < 20) ? (pP + 4 * jq)
                     : (jq < 32) ? (pC + 4 * (jq - 20))
                     : (jq < 36) ? (pA + 4 * (jq - 32))
                     : (pE + 4 * (jq - 36));
      float4 v = *reinterpret_cast<const float4*>(p);
      uint2 o;
      o.x = pkrtz_u(v.x, v.y);
      o.y = pkrtz_u(v.z, v.w);
      *reinterpret_cast<uint2*>(orow + 4 * jq) = o;
    }
  }
}

// ---------------------------------------------------------------------------
// Fused 2-layer GEMM over permuted edges, pure-stream A:
//  - A-data (x values + pre-converted ea) read SEQUENTIALLY from xgp.
//  - W per K128-chunk in LDS (double buffer, padded rows) -> B via lgkmcnt,
//    A via vmcnt: decoupled wait counters.
//  - m1 crosses layers in LDS [256][72] f16; m2 written coalesced PERM order.
//  - 512 thr = 8 waves = 4 wm x 2 wn; block tile 256 edges x 64 h.
// ---------------------------------------------------------------------------
__global__ __launch_bounds__(512, 4) void fused_gemm_kernel(
    const _Float16* __restrict__ xgp,
    const _Float16* __restrict__ wt1, const float* __restrict__ b1,
    const _Float16* __restrict__ wt2, const float* __restrict__ b2,
    _Float16* __restrict__ m2p)
{
  constexpr int CHROW = 136;                // padded chunk row (f16)
  __shared__ _Float16 s_w[2][64 * CHROW];   // 34.8 KB
  __shared__ _Float16 s_m1[256 * 72];       // 36.9 KB

  const int t    = threadIdx.x;
  const int lane = t & 63;
  const int wv   = t >> 6;
  const int wm   = wv >> 1;             // 0..3 edge quarter
  const int wn   = wv & 1;              // 0..1 h half
  const int l15  = lane & 15;
  const int q    = lane >> 4;           // 0..3

  const int EB = blockIdx.x * 256;      // position base (perm space)

  // staging geometry (both layers)
  const int idx0 = t * 2, idx1 = t * 2 + 1;
  const int h0 = idx0 >> 4, sl0 = idx0 & 15;
  const int h1 = idx1 >> 4, sl1 = idx1 & 15;
  const int lo0 = h0 * CHROW + sl0 * 8, lo1 = h1 * CHROW + sl1 * 8;
  const size_t g0_1 = (size_t)h0 * K1 + sl0 * 8, g1_1 = (size_t)h1 * K1 + sl1 * 8;
  const size_t g0_2 = (size_t)h0 * K2 + sl0 * 8, g1_2 = (size_t)h1 * K2 + sl1 * 8;

  // per-mt: ea fragments (pre-converted, 16B aligned) + x stream base
  f16x2 apk[4][4];
  size_t xbase[4];
  #pragma unroll
  for (int mt = 0; mt < 4; ++mt){
    const size_t pos = EB + wm * 64 + mt * 16 + l15;
    U4F2 af;
    af.u = *reinterpret_cast<const uint4*>(xgp + pos * XROW + 144);
    apk[mt][0] = af.h2[0];
    apk[mt][1] = af.h2[1];
    apk[mt][2] = af.h2[2];
    apk[mt][3] = af.h2[3];
    xbase[mt] = pos * XROW + q * 36;
  }

  f32x4 acc[4][2];
  #pragma unroll
  for (int mt = 0; mt < 4; ++mt){
    acc[mt][0] = f32x4{0.f,0.f,0.f,0.f};
    acc[mt][1] = f32x4{0.f,0.f,0.f,0.f};
  }

  uint2 xc[4], xn[4];
  auto FETCHX = [&](int c, uint2* dstv){
    #pragma unroll
    for (int mt = 0; mt < 4; ++mt)
      dstv[mt] = *reinterpret_cast<const uint2*>(xgp + xbase[mt] + 4 * c);
  };

  const int wrow = (wn * 32 + l15) * CHROW + q * 8;

  // ================= LAYER 1 (9 chunks of K=128) =================
  uint4 wr0 = *reinterpret_cast<const uint4*>(wt1 + g0_1);
  uint4 wr1 = *reinterpret_cast<const uint4*>(wt1 + g1_1);
  FETCHX(0, xc);
  *reinterpret_cast<uint4*>(&s_w[0][lo0]) = wr0;
  *reinterpret_cast<uint4*>(&s_w[0][lo1]) = wr1;
  __syncthreads();

  for (int c = 0; c < 9; ++c){
    if (c < 8){
      wr0 = *reinterpret_cast<const uint4*>(wt1 + g0_1 + (c + 1) * 128);
      wr1 = *reinterpret_cast<const uint4*>(wt1 + g1_1 + (c + 1) * 128);
      FETCHX(c + 1, xn);
    }
    const _Float16* buf = s_w[c & 1];
    #pragma unroll
    for (int ksl = 0; ksl < 4; ++ksl){
      f16x8 Bf[2];
      #pragma unroll
      for (int nt = 0; nt < 2; ++nt)
        Bf[nt] = __builtin_bit_cast(f16x8,
            *reinterpret_cast<const uint4*>(&buf[wrow + nt * 16 * CHROW + ksl * 32]));
      #pragma unroll
      for (int mt = 0; mt < 4; ++mt){
        const unsigned comp = (ksl < 2) ? xc[mt].x : xc[mt].y;
        const unsigned v = (ksl & 1) ? (comp >> 16) : (comp & 0xffffu);
        f16x2 xh = __builtin_bit_cast(f16x2, v | (v << 16));
        F16x8U A;
        #pragma unroll
        for (int j = 0; j < 4; ++j) A.h2[j] = xh * apk[mt][j];
        acc[mt][0] = __builtin_amdgcn_mfma_f32_16x16x32_f16(A.v8, Bf[0], acc[mt][0], 0, 0, 0);
        acc[mt][1] = __builtin_amdgcn_mfma_f32_16x16x32_f16(A.v8, Bf[1], acc[mt][1], 0, 0, 0);
      }
    }
    if (c < 8){
      _Float16* nb = s_w[(c + 1) & 1];
      *reinterpret_cast<uint4*>(&nb[lo0]) = wr0;
      *reinterpret_cast<uint4*>(&nb[lo1]) = wr1;
      #pragma unroll
      for (int mt = 0; mt < 4; ++mt) xc[mt] = xn[mt];
    }
    __syncthreads();
  }

  // issue layer-2 chunk-0 W loads early
  wr0 = *reinterpret_cast<const uint4*>(wt2 + g0_2);
  wr1 = *reinterpret_cast<const uint4*>(wt2 + g1_2);

  // ---- epilogue 1: +b1, SiLU -> s_m1 (f16). C/D: col=l15, row=q*4+r
  {
    float bv[2];
    bv[0] = b1[wn * 32 + l15];
    bv[1] = b1[wn * 32 + 16 + l15];
    #pragma unroll
    for (int mt = 0; mt < 4; ++mt){
      #pragma unroll
      for (int nt = 0; nt < 2; ++nt){
        #pragma unroll
        for (int r = 0; r < 4; ++r){
          float s = silu_f(acc[mt][nt][r] + bv[nt]);
          const int eo = wm * 64 + mt * 16 + q * 4 + r;
          const int h  = wn * 32 + nt * 16 + l15;
          s_m1[eo * 72 + h] = (_Float16)s;
        }
      }
    }
  }
  __syncthreads();

  // ---- preload layer-2 A-data from LDS m1; stage W2 chunk 0
  uint4 md[4][2];
  #pragma unroll
  for (int mt = 0; mt < 4; ++mt){
    const int eo = wm * 64 + mt * 16 + l15;
    const uint4* mp = reinterpret_cast<const uint4*>(&s_m1[eo * 72 + q * 16]);
    md[mt][0] = mp[0];
    md[mt][1] = mp[1];
    acc[mt][0] = f32x4{0.f,0.f,0.f,0.f};
    acc[mt][1] = f32x4{0.f,0.f,0.f,0.f};
  }
  *reinterpret_cast<uint4*>(&s_w[0][lo0]) = wr0;
  *reinterpret_cast<uint4*>(&s_w[0][lo1]) = wr1;
  __syncthreads();

  // ================= LAYER 2 (4 chunks of K=128) =================
  for (int c = 0; c < 4; ++c){
    if (c < 3){
      wr0 = *reinterpret_cast<const uint4*>(wt2 + g0_2 + (c + 1) * 128);
      wr1 = *reinterpret_cast<const uint4*>(wt2 + g1_2 + (c + 1) * 128);
    }
    const _Float16* buf = s_w[c & 1];
    #pragma unroll
    for (int ksl = 0; ksl < 4; ++ksl){
      f16x8 Bf[2];
      #pragma unroll
      for (int nt = 0; nt < 2; ++nt)
        Bf[nt] = __builtin_bit_cast(f16x8,
            *reinterpret_cast<const uint4*>(&buf[wrow + nt * 16 * CHROW + ksl * 32]));
      const int ks = c * 4 + ksl;
      #pragma unroll
      for (int mt = 0; mt < 4; ++mt){
        const unsigned comp = (ks < 8)
            ? ((ks >> 1) == 0 ? md[mt][0].x : (ks >> 1) == 1 ? md[mt][0].y
             : (ks >> 1) == 2 ? md[mt][0].z : md[mt][0].w)
            : (((ks - 8) >> 1) == 0 ? md[mt][1].x : ((ks - 8) >> 1) == 1 ? md[mt][1].y
             : ((ks - 8) >> 1) == 2 ? md[mt][1].z : md[mt][1].w);
        const unsigned v = (ks & 1) ? (comp >> 16) : (comp & 0xffffu);
        f16x2 xh = __builtin_bit_cast(f16x2, v | (v << 16));
        F16x8U A;
        #pragma unroll
        for (int j = 0; j < 4; ++j) A.h2[j] = xh * apk[mt][j];
        acc[mt][0] = __builtin_amdgcn_mfma_f32_16x16x32_f16(A.v8, Bf[0], acc[mt][0], 0, 0, 0);
        acc[mt][1] = __builtin_amdgcn_mfma_f32_16x16x32_f16(A.v8, Bf[1], acc[mt][1], 0, 0, 0);
      }
    }
    if (c < 3){
      _Float16* nb = s_w[(c + 1) & 1];
      *reinterpret_cast<uint4*>(&nb[lo0]) = wr0;
      *reinterpret_cast<uint4*>(&nb[lo1]) = wr1;
    }
    __syncthreads();
  }

  // ---- epilogue 2: +b2, SiLU -> m2p (perm order, coalesced)
  {
    float bv[2];
    bv[0] = b2[wn * 32 + l15];
    bv[1] = b2[wn * 32 + 16 + l15];
    #pragma unroll
    for (int mt = 0; mt < 4; ++mt){
      #pragma unroll
      for (int nt = 0; nt < 2; ++nt){
        #pragma unroll
        for (int r = 0; r < 4; ++r){
          float s = silu_f(acc[mt][nt][r] + bv[nt]);
          const int eo = wm * 64 + mt * 16 + q * 4 + r;
          const int h  = wn * 32 + nt * 16 + l15;
          m2p[(size_t)(EB + eo) * 64 + h] = (_Float16)s;
        }
      }
    }
  }
}

// ---------------------------------------------------------------------------
// combine: out[n] = concat(x_p[n], sum_{j<d} m2p[off[n]+j])   (8 lanes/node)
// ---------------------------------------------------------------------------
__global__ __launch_bounds__(256) void combine_kernel(
    const float* __restrict__ x_p, const int* __restrict__ cnt,
    const int* __restrict__ off, const _Float16* __restrict__ m2p,
    float* __restrict__ out)
{
  const int gid = blockIdx.x * 256 + threadIdx.x;
  const int n = gid >> 3;
  const int r = gid & 7;
  const float* ps = x_p + (size_t)n * D_P;
  float* po = out + (size_t)n * 144;
  #pragma unroll
  for (int i = 0; i < 3; ++i){
    const int j4 = r + 8 * i;
    if (j4 < 20)
      *reinterpret_cast<float4*>(po + 4 * j4) = *reinterpret_cast<const float4*>(ps + 4 * j4);
  }
  float s[8] = {0.f,0.f,0.f,0.f,0.f,0.f,0.f,0.f};
  const int o0 = off[n];
  const int d  = min(cnt[n], MAXDEG);
  for (int j = 0; j < d; ++j){
    const uint4 mv = *reinterpret_cast<const uint4*>(m2p + (size_t)(o0 + j) * 64 + r * 8);
    f16x8 mh = __builtin_bit_cast(f16x8, mv);
    #pragma unroll
    for (int k = 0; k < 8; ++k) s[k] += (float)mh[k];
  }
  float4 o0v = make_float4(s[0], s[1], s[2], s[3]);
  float4 o1v = make_float4(s[4], s[5], s[6], s[7]);
  *reinterpret_cast<float4*>(po + 80 + r * 8)     = o0v;
  *reinterpret_cast<float4*>(po + 80 + r * 8 + 4) = o1v;
}

extern "C" void kernel_launch(void* const* d_in, const int* in_sizes, int n_in,
                              void* d_out, int out_size, void* d_ws, size_t ws_size,
                              hipStream_t stream){
  const float* x_p  = (const float*)d_in[0];
  const float* x_c  = (const float*)d_in[1];
  const int*   eidx = (const int*)d_in[2];
  const float* ea   = (const float*)d_in[3];
  // d_in[4] = batch (unused)
  const float* addf = (const float*)d_in[5];
  const float* W1   = (const float*)d_in[6];
  const float* b1   = (const float*)d_in[7];
  const float* W2   = (const float*)d_in[8];
  const float* b2   = (const float*)d_in[9];
  float* out = (float*)d_out;

  char* ws = (char*)d_ws;
  _Float16* wt1 = (_Float16*)(ws);                 // 147456 B
  _Float16* wt2 = (_Float16*)(ws + 163840);        //  65536 B
  int* cnt   = (int*)(ws + 262144);                // 256 KB
  int* bsum  = (int*)(ws + 524288);                // 1 KB
  int* boff  = (int*)(ws + 525312);                // 1 KB
  int* off   = (int*)(ws + 526336);                // 256 KB
  int* slots = (int*)(ws + 788480);                // 8 MB
  int* perm  = (int*)(ws + 9177088);               // 512 KB
  _Float16* m2p = (_Float16*)(ws + 9701376);       // 16.78 MB
  _Float16* xgp = (_Float16*)(ws + 26478592);      // 39.85 MB (E*152 f16)

  prep_w_kernel<<<(64 * K1 + 64 * K2) / 256, 256, 0, stream>>>(W1, W2, wt1, wt2);
  zero_cnt_kernel<<<(NP_CNT + 256) / 256, 256, 0, stream>>>(cnt, bsum);
  fill_slots_kernel<<<E_CNT / 256, 256, 0, stream>>>(eidx, cnt, slots);
  scanA_kernel<<<NP_CNT / 256, 256, 0, stream>>>(cnt, bsum);
  scanB_kernel<<<1, 256, 0, stream>>>(bsum, boff);
  scanC_emit_kernel<<<NP_CNT / 256, 256, 0, stream>>>(cnt, slots, boff, off, perm);
  gather_perm_kernel<<<E_CNT * 8 / 256, 256, 0, stream>>>(x_p, x_c, addf, ea, eidx, perm, xgp);
  fused_gemm_kernel<<<E_CNT / 256, 512, 0, stream>>>(xgp, wt1, b1, wt2, b2, m2p);
  combine_kernel<<<NP_CNT * 8 / 256, 256, 0, stream>>>(x_p, cnt, off, m2p, out);
}